// Round 1
// baseline (284.941 us; speedup 1.0000x reference)
//
#include <hip/hip_runtime.h>
#include <math.h>

// Problem constants
#define NB   16
#define NC   64
#define HWs  4096
#define NPS  1024
#define LOG2E 1.44269504088896341f

// ws layout in ushort (bf16 bit patterns)
static constexpr size_t PHI_OFF = (size_t)NB * HWs * 8;            // theta: [b][4096][8]
static constexpr size_t GT_OFF  = PHI_OFF + (size_t)NB * NPS * 8;  // phi:   [b][1024][8]
// gT: [b][32][1024]; total 1,179,648 ushorts = 2.25 MB

typedef short s16x8 __attribute__((ext_vector_type(8)));
typedef float f32x4 __attribute__((ext_vector_type(4)));

#define LD8G(p) (*(const s16x8*)(p))

__device__ inline unsigned short f2bf(float f) {
    unsigned int u = __float_as_uint(f);
    u += 0x7fffu + ((u >> 16) & 1u);          // RNE
    return (unsigned short)(u >> 16);
}
__device__ inline unsigned int pk2(float a, float b) {
    unsigned int ua = __float_as_uint(a); ua += 0x7fffu + ((ua >> 16) & 1u);
    unsigned int ub = __float_as_uint(b); ub += 0x7fffu + ((ub >> 16) & 1u);
    return (ua >> 16) | (ub & 0xffff0000u);
}

// ---------------------------------------------------------------------------
// Kernel 1 (v3): all projections in one pass, x staged through LDS.
// Unchanged this round (no counters yet; will surface in top-5 once k_attn
// drops below it).
// ---------------------------------------------------------------------------
__global__ __launch_bounds__(256) void k_proj(
    const float* __restrict__ x, const float* __restrict__ Wt,
    const float* __restrict__ Wp, const float* __restrict__ Wg,
    unsigned short* __restrict__ ws)
{
    __shared__ float xs[64 * 128];            // 32 KB

    unsigned short* theta = ws;
    unsigned short* phi   = ws + PHI_OFF;
    unsigned short* gT    = ws + GT_OFF;

    const int tid = threadIdx.x;
    const int blk = blockIdx.x;
    const int b   = blk >> 5;
    const int rp  = blk & 31;                 // image rows {2rp, 2rp+1}

    // ---- stage x[b][ci][rp*128 .. +128) -> xs[ci][0..128) ----
    const float* xsrc = x + (size_t)b * NC * HWs + rp * 128;
#pragma unroll
    for (int i = 0; i < 8; ++i) {
        const int idx = i * 256 + tid;        // 0..2047 float4 slots
        const int ci  = idx >> 5;
        const int f4  = idx & 31;
        float4 v = *(const float4*)(xsrc + (size_t)ci * HWs + f4 * 4);
        *(float4*)(xs + ci * 128 + f4 * 4) = v;
    }
    __syncthreads();

    const int h    = tid & 127;
    // wave-uniform in fact (waves 0,1 -> 0; waves 2,3 -> 1); force to SGPR
    const int half = __builtin_amdgcn_readfirstlane(tid >> 7);
    const int row  = h & 1;
    const int col  = h >> 1;
    const int px   = row * 64 + col;

    float a8[8], ag[16];
#pragma unroll
    for (int j = 0; j < 8; ++j)  a8[j] = 0.f;
#pragma unroll
    for (int j = 0; j < 16; ++j) ag[j] = 0.f;

    const float* W8 = half ? Wp : Wt;         // scalar select (half is SGPR)
    const float* WG = Wg + half * 16 * NC;

#pragma unroll 4
    for (int ci = 0; ci < NC; ++ci) {
        const float xv = xs[ci * 128 + px];   // 2-way bank alias: free
#pragma unroll
        for (int j = 0; j < 8; ++j)  a8[j] += W8[j * NC + ci] * xv;   // s_load
#pragma unroll
        for (int j = 0; j < 16; ++j) ag[j] += WG[j * NC + ci] * xv;   // s_load
    }

    if (half == 0) {
        // theta: unpooled, scaled by log2e
        const int q = (2 * rp + row) * 64 + col;
        uint4 pkd;
        pkd.x = pk2(a8[0] * LOG2E, a8[1] * LOG2E);
        pkd.y = pk2(a8[2] * LOG2E, a8[3] * LOG2E);
        pkd.z = pk2(a8[4] * LOG2E, a8[5] * LOG2E);
        pkd.w = pk2(a8[6] * LOG2E, a8[7] * LOG2E);
        *(uint4*)(theta + ((size_t)b * HWs + q) * 8) = pkd;
    }

    // pooled max: row pair (h^1) then col pair (h^2) — both within-wave
#pragma unroll
    for (int j = 0; j < 8; ++j) {
        float v = a8[j];
        v = fmaxf(v, __shfl_xor(v, 1));
        v = fmaxf(v, __shfl_xor(v, 2));
        a8[j] = v;
    }
#pragma unroll
    for (int j = 0; j < 16; ++j) {
        float v = ag[j];
        v = fmaxf(v, __shfl_xor(v, 1));
        v = fmaxf(v, __shfl_xor(v, 2));
        ag[j] = v;
    }

    if ((h & 3) == 0) {
        const int ps = rp * 32 + (h >> 2);
        if (half == 1) {
            uint4 pkd;
            pkd.x = pk2(a8[0], a8[1]); pkd.y = pk2(a8[2], a8[3]);
            pkd.z = pk2(a8[4], a8[5]); pkd.w = pk2(a8[6], a8[7]);
            *(uint4*)(phi + ((size_t)b * NPS + ps) * 8) = pkd;
        }
#pragma unroll
        for (int j = 0; j < 16; ++j) {
            const int c = half * 16 + j;
            gT[((size_t)b * 32 + c) * NPS + ps] = f2bf(ag[j]);
        }
    }
}

// ---------------------------------------------------------------------------
// Kernel 2 (v4): s-split for occupancy.
// Round-5 analysis: v3 at 50 us, MfmaUtil 6%, VALUBusy 44%, Occ 33% =
// latency-bound; 4096 waves vs 8192 slots caps occupancy at <=50%.
// v4: block = 512 thr / 8 waves; wave w -> (q-subtile w&3, s-half w>>2),
// 8 tiles each. Partial (O,l) per s-half combined through LDS (exp2 is of
// raw scores, no running max, so partials sum exactly). Grid 1024 x 8 waves
// = 8192 waves = 100% of device slots; LDS 36864 B -> 4 blocks/CU, matching
// launch_bounds(512,8) (VGPR<=64; v3 body measured 60).
// Tile-loop body identical to v3 (prefetch pipeline, lagged PV, dbuf P).
// ---------------------------------------------------------------------------
__global__ __launch_bounds__(512, 8) void k_attn(
    const float* __restrict__ x, const float* __restrict__ Wo,
    const float* __restrict__ gamma_p, const unsigned short* __restrict__ ws,
    float* __restrict__ out)
{
    // P: 8 waves x 2 bufs x [16 q][72 s] bf16 = 36864 B.
    // Post-loop (after barrier) the same region is reused as:
    //   xO  [4 qw][32 c][16 q] f32   floats [0,2048)
    //   xl  [64 q] f32               floats [2048,2112)
    //   otile [32 c][68 q] f32       floats [2112,4288)
    __shared__ __align__(16) unsigned char smem[36864];

    const int tid  = threadIdx.x;
    const int wave = __builtin_amdgcn_readfirstlane(tid >> 6);  // 0..7
    const int qw   = wave & 3;                // q sub-tile
    const int sh   = wave >> 2;               // s half
    const int lane = tid & 63;
    const int quad = lane >> 4, lr = lane & 15;
    const int blk  = blockIdx.x;
    const int b    = blk >> 6;
    const int q0   = (blk & 63) * 64;
    const int sBase = sh * 512;

    const unsigned short* th = ws + (size_t)b * HWs * 8;
    const unsigned short* ph = ws + PHI_OFF + (size_t)b * NPS * 8 + (size_t)sBase * 8;
    const unsigned short* gp = ws + GT_OFF + (size_t)b * 32 * NPS + sBase;
    unsigned short* Pw = (unsigned short*)smem + wave * 2304;   // 2 bufs x [16][72]

    const s16x8 zf = {0, 0, 0, 0, 0, 0, 0, 0};

    // theta A-fragment: A[m=q=lr][k=quad*8+j], real k<8 in quad 0
    const s16x8 thA = (quad == 0) ? LD8G(th + (size_t)(q0 + qw * 16 + lr) * 8) : zf;

    f32x4 O[2];
    f32x4 l4;
#pragma unroll
    for (int r = 0; r < 4; ++r) { O[0][r] = 0.f; O[1][r] = 0.f; l4[r] = 0.f; }

    // pipeline registers
    s16x8 phB_c[4], phB_n[4];
    s16x8 Gf_c[2][2], Gf_n[2][2];
#pragma unroll
    for (int ss = 0; ss < 4; ++ss)
        phB_c[ss] = (quad == 0) ? LD8G(ph + (size_t)(ss * 16 + lr) * 8) : zf;

    for (int t = 0; t < 8; ++t) {
        const int s0 = t * 64;
        const int sn = (t < 7 ? t + 1 : 7) * 64;

        // ---- prefetch next phB and this tile's Gf (consumed next iter) ----
#pragma unroll
        for (int ss = 0; ss < 4; ++ss)
            phB_n[ss] = (quad == 0) ? LD8G(ph + (size_t)(sn + ss * 16 + lr) * 8) : zf;
#pragma unroll
        for (int kc = 0; kc < 2; ++kc)
#pragma unroll
            for (int cs = 0; cs < 2; ++cs)
                Gf_n[kc][cs] = LD8G(gp + (size_t)(cs * 16 + lr) * NPS + s0 + kc * 32 + quad * 8);

        // ---- scores for tile t (phB_c prefetched last iter) ----
        const f32x4 zc = {0.f, 0.f, 0.f, 0.f};
        f32x4 S[4];
#pragma unroll
        for (int ss = 0; ss < 4; ++ss)
            S[ss] = __builtin_amdgcn_mfma_f32_16x16x32_bf16(thA, phB_c[ss], zc, 0, 0, 0);

        // ---- lagged PV for tile t-1 (P read from buf (t-1)&1, Gf_c prefetched) ----
        if (t > 0) {
            const unsigned short* Pb = Pw + ((t - 1) & 1) * 1152;
#pragma unroll
            for (int kc = 0; kc < 2; ++kc) {
                const s16x8 Pf = *(const s16x8*)(Pb + lr * 72 + kc * 32 + quad * 8);
#pragma unroll
                for (int cs = 0; cs < 2; ++cs)
                    O[cs] = __builtin_amdgcn_mfma_f32_16x16x32_bf16(Pf, Gf_c[kc][cs], O[cs], 0, 0, 0);
            }
        }

        // ---- p = exp2(S), accumulate l, store bf16 P to buf t&1 ----
        unsigned short* Pbw = Pw + (t & 1) * 1152;
#pragma unroll
        for (int ss = 0; ss < 4; ++ss)
#pragma unroll
            for (int r = 0; r < 4; ++r) {
                const float p = exp2f(S[ss][r]);
                l4[r] += p;
                Pbw[(quad * 4 + r) * 72 + ss * 16 + lr] =
                    (unsigned short)(__float_as_uint(p) >> 16);   // truncate
            }

        // ---- rotate pipeline ----
#pragma unroll
        for (int ss = 0; ss < 4; ++ss) phB_c[ss] = phB_n[ss];
#pragma unroll
        for (int kc = 0; kc < 2; ++kc)
#pragma unroll
            for (int cs = 0; cs < 2; ++cs) Gf_c[kc][cs] = Gf_n[kc][cs];
    }

    // ---- drain: PV for tile 7 ----
    {
        const unsigned short* Pb = Pw + (7 & 1) * 1152;
#pragma unroll
        for (int kc = 0; kc < 2; ++kc) {
            const s16x8 Pf = *(const s16x8*)(Pb + lr * 72 + kc * 32 + quad * 8);
#pragma unroll
            for (int cs = 0; cs < 2; ++cs)
                O[cs] = __builtin_amdgcn_mfma_f32_16x16x32_bf16(Pf, Gf_c[kc][cs], O[cs], 0, 0, 0);
        }
    }

    // l partial: butterfly-sum over the 16-lane s-groups (no reciprocal yet —
    // the two s-halves still need combining)
#pragma unroll
    for (int r = 0; r < 4; ++r) {
        float v = l4[r];
        v += __shfl_xor(v, 1);
        v += __shfl_xor(v, 2);
        v += __shfl_xor(v, 4);
        v += __shfl_xor(v, 8);
        l4[r] = v;
    }

    __syncthreads();                          // all waves past their last P read
    float* xO    = (float*)smem;              // [4 qw][32 c][16 q]
    float* xl    = xO + 2048;                 // [64 q]
    float* otile = xl + 64;                   // [32 c][68 q]

    if (sh == 1) {
        // publish partial O and l
#pragma unroll
        for (int cs = 0; cs < 2; ++cs) {
            f32x4 v;
#pragma unroll
            for (int r = 0; r < 4; ++r) v[r] = O[cs][r];
            *(f32x4*)(xO + qw * 512 + (cs * 16 + lr) * 16 + quad * 4) = v;
        }
        if (lr == 0) {
#pragma unroll
            for (int r = 0; r < 4; ++r) xl[qw * 16 + quad * 4 + r] = l4[r];
        }
    }
    __syncthreads();
    if (sh == 0) {
        // combine halves, normalize, write otile
        f32x4 rl;
#pragma unroll
        for (int r = 0; r < 4; ++r)
            rl[r] = 1.f / (l4[r] + xl[qw * 16 + quad * 4 + r]);
#pragma unroll
        for (int cs = 0; cs < 2; ++cs) {
            const f32x4 xv = *(const f32x4*)(xO + qw * 512 + (cs * 16 + lr) * 16 + quad * 4);
            f32x4 v;
#pragma unroll
            for (int r = 0; r < 4; ++r) v[r] = (O[cs][r] + xv[r]) * rl[r];
            *(f32x4*)(otile + (cs * 16 + lr) * 68 + qw * 16 + quad * 4) = v;
        }
    }
    __syncthreads();

    // Wo epilogue + residual: thread = (q = tid&63, oc group of 8 = wave)
    const int qq = tid & 63;
    const int ocg = wave;                     // SGPR -> s_load Wo
    float acc[8];
#pragma unroll
    for (int j = 0; j < 8; ++j) acc[j] = 0.f;
    for (int c = 0; c < 32; ++c) {
        const float ov = otile[c * 68 + qq];
#pragma unroll
        for (int j = 0; j < 8; ++j)
            acc[j] += Wo[(ocg * 8 + j) * 32 + c] * ov;   // s_load
    }
    const float gam = gamma_p[0];
#pragma unroll
    for (int j = 0; j < 8; ++j) {
        const size_t a = ((size_t)b * NC + ocg * 8 + j) * HWs + q0 + qq;
        out[a] = gam * acc[j] + x[a];
    }
}

extern "C" void kernel_launch(void* const* d_in, const int* in_sizes, int n_in,
                              void* d_out, int out_size, void* d_ws, size_t ws_size,
                              hipStream_t stream) {
    const float* x     = (const float*)d_in[0];
    const float* Wt    = (const float*)d_in[1];
    const float* Wp    = (const float*)d_in[2];
    const float* Wg    = (const float*)d_in[3];
    const float* Wo    = (const float*)d_in[4];
    const float* gamma = (const float*)d_in[5];
    float* out = (float*)d_out;
    unsigned short* ws = (unsigned short*)d_ws;

    k_proj<<<512, 256, 0, stream>>>(x, Wt, Wp, Wg, ws);
    k_attn<<<1024, 512, 0, stream>>>(x, Wo, gamma, ws, out);
}

// Round 2
// 150.361 us; speedup vs baseline: 1.8950x; 1.8950x over previous
//
#include <hip/hip_runtime.h>
#include <math.h>

// Problem constants
#define NB   16
#define NC   64
#define HWs  4096
#define NPS  1024
#define LOG2E 1.44269504088896341f

// ws layout in ushort (bf16 bit patterns)
static constexpr size_t PHI_OFF = (size_t)NB * HWs * 8;            // theta: [b][4096][8]
static constexpr size_t GT_OFF  = PHI_OFF + (size_t)NB * NPS * 8;  // phi:   [b][1024][8]
// gT: [b][32][1024]; total 1,179,648 ushorts = 2.25 MB

typedef short s16x8 __attribute__((ext_vector_type(8)));
typedef float f32x4 __attribute__((ext_vector_type(4)));

#define LD8G(p) (*(const s16x8*)(p))

__device__ inline unsigned short f2bf(float f) {
    unsigned int u = __float_as_uint(f);
    u += 0x7fffu + ((u >> 16) & 1u);          // RNE
    return (unsigned short)(u >> 16);
}
__device__ inline unsigned int pk2(float a, float b) {
    unsigned int ua = __float_as_uint(a); ua += 0x7fffu + ((ua >> 16) & 1u);
    unsigned int ub = __float_as_uint(b); ub += 0x7fffu + ((ub >> 16) & 1u);
    return (ua >> 16) | (ub & 0xffff0000u);
}

// ---------------------------------------------------------------------------
// Kernel 1 (v3): all projections in one pass, x staged through LDS.
// Unchanged (still below top-5; will be the target once k_attn drops).
// ---------------------------------------------------------------------------
__global__ __launch_bounds__(256) void k_proj(
    const float* __restrict__ x, const float* __restrict__ Wt,
    const float* __restrict__ Wp, const float* __restrict__ Wg,
    unsigned short* __restrict__ ws)
{
    __shared__ float xs[64 * 128];            // 32 KB

    unsigned short* theta = ws;
    unsigned short* phi   = ws + PHI_OFF;
    unsigned short* gT    = ws + GT_OFF;

    const int tid = threadIdx.x;
    const int blk = blockIdx.x;
    const int b   = blk >> 5;
    const int rp  = blk & 31;                 // image rows {2rp, 2rp+1}

    // ---- stage x[b][ci][rp*128 .. +128) -> xs[ci][0..128) ----
    const float* xsrc = x + (size_t)b * NC * HWs + rp * 128;
#pragma unroll
    for (int i = 0; i < 8; ++i) {
        const int idx = i * 256 + tid;        // 0..2047 float4 slots
        const int ci  = idx >> 5;
        const int f4  = idx & 31;
        float4 v = *(const float4*)(xsrc + (size_t)ci * HWs + f4 * 4);
        *(float4*)(xs + ci * 128 + f4 * 4) = v;
    }
    __syncthreads();

    const int h    = tid & 127;
    // wave-uniform in fact (waves 0,1 -> 0; waves 2,3 -> 1); force to SGPR
    const int half = __builtin_amdgcn_readfirstlane(tid >> 7);
    const int row  = h & 1;
    const int col  = h >> 1;
    const int px   = row * 64 + col;

    float a8[8], ag[16];
#pragma unroll
    for (int j = 0; j < 8; ++j)  a8[j] = 0.f;
#pragma unroll
    for (int j = 0; j < 16; ++j) ag[j] = 0.f;

    const float* W8 = half ? Wp : Wt;         // scalar select (half is SGPR)
    const float* WG = Wg + half * 16 * NC;

#pragma unroll 4
    for (int ci = 0; ci < NC; ++ci) {
        const float xv = xs[ci * 128 + px];   // 2-way bank alias: free
#pragma unroll
        for (int j = 0; j < 8; ++j)  a8[j] += W8[j * NC + ci] * xv;   // s_load
#pragma unroll
        for (int j = 0; j < 16; ++j) ag[j] += WG[j * NC + ci] * xv;   // s_load
    }

    if (half == 0) {
        // theta: unpooled, scaled by log2e
        const int q = (2 * rp + row) * 64 + col;
        uint4 pkd;
        pkd.x = pk2(a8[0] * LOG2E, a8[1] * LOG2E);
        pkd.y = pk2(a8[2] * LOG2E, a8[3] * LOG2E);
        pkd.z = pk2(a8[4] * LOG2E, a8[5] * LOG2E);
        pkd.w = pk2(a8[6] * LOG2E, a8[7] * LOG2E);
        *(uint4*)(theta + ((size_t)b * HWs + q) * 8) = pkd;
    }

    // pooled max: row pair (h^1) then col pair (h^2) — both within-wave
#pragma unroll
    for (int j = 0; j < 8; ++j) {
        float v = a8[j];
        v = fmaxf(v, __shfl_xor(v, 1));
        v = fmaxf(v, __shfl_xor(v, 2));
        a8[j] = v;
    }
#pragma unroll
    for (int j = 0; j < 16; ++j) {
        float v = ag[j];
        v = fmaxf(v, __shfl_xor(v, 1));
        v = fmaxf(v, __shfl_xor(v, 2));
        ag[j] = v;
    }

    if ((h & 3) == 0) {
        const int ps = rp * 32 + (h >> 2);
        if (half == 1) {
            uint4 pkd;
            pkd.x = pk2(a8[0], a8[1]); pkd.y = pk2(a8[2], a8[3]);
            pkd.z = pk2(a8[4], a8[5]); pkd.w = pk2(a8[6], a8[7]);
            *(uint4*)(phi + ((size_t)b * NPS + ps) * 8) = pkd;
        }
#pragma unroll
        for (int j = 0; j < 16; ++j) {
            const int c = half * 16 + j;
            gT[((size_t)b * 32 + c) * NPS + ps] = f2bf(ag[j]);
        }
    }
}

// ---------------------------------------------------------------------------
// Kernel 2 (v5): s-split for occupancy, v3's register configuration.
// Round-6 post-mortem: v4's launch_bounds(512,8) forced a 64-VGPR cap on a
// ~100-VGPR-live-state body -> catastrophic scratch spill (FETCH 14->234 MB,
// WRITE 16->421 MB, 671 MB HBM = the whole 208 us). Occupancy DID rise
// (33->65%), so the s-split theory stands; the delivery was wrong.
// v5: 2048 blocks x 256 thr (4 waves) — the exact block shape + plain
// launch_bounds(256) that compiled this body to 60 VGPR, no spill, in v3.
// Block = (b, 32-q tile); wave = (qsub 0..1, s-half 0..1); 8 s-tiles/wave.
// Partial (O,l) combined through LDS (exact: exp2 of raw scores, no max).
// Occupancy: VGPR ~60 -> 8 w/SIMD; LDS 18432 -> 8 blk/CU; 2048 blk / 256 CU
// = 8 blk/CU = 32 waves/CU. 8192 waves = 100% of device slots.
// ---------------------------------------------------------------------------
__global__ __launch_bounds__(256) void k_attn(
    const float* __restrict__ x, const float* __restrict__ Wo,
    const float* __restrict__ gamma_p, const unsigned short* __restrict__ ws,
    float* __restrict__ out)
{
    // P: 4 waves x 2 bufs x [16 q][72 s] bf16 = 18432 B.
    // Post-loop reuse (floats): xO [2 qsub][32 c][16 q] = [0,1024);
    //   otile [32 c][36 q-stride] = [1024,2176); xl [2 qsub][16 q] = [2176,2208).
    __shared__ __align__(16) unsigned char smem[18432];

    const int tid  = threadIdx.x;
    const int wave = __builtin_amdgcn_readfirstlane(tid >> 6);  // 0..3
    const int qsub = wave & 1;                // q sub-tile (16 rows)
    const int sh   = wave >> 1;               // s half (512 keys)
    const int lane = tid & 63;
    const int quad = lane >> 4, lr = lane & 15;
    const int blk  = blockIdx.x;
    const int b    = blk >> 7;
    const int q0   = (blk & 127) * 32;
    const int sBase = sh * 512;

    const unsigned short* th = ws + (size_t)b * HWs * 8;
    const unsigned short* ph = ws + PHI_OFF + (size_t)b * NPS * 8 + (size_t)sBase * 8;
    const unsigned short* gp = ws + GT_OFF + (size_t)b * 32 * NPS + sBase;
    unsigned short* Pw = (unsigned short*)smem + wave * 2304;   // 2 bufs x [16][72]

    const s16x8 zf = {0, 0, 0, 0, 0, 0, 0, 0};

    // theta A-fragment: A[m=q=lr][k=quad*8+j], real k<8 in quad 0
    const s16x8 thA = (quad == 0) ? LD8G(th + (size_t)(q0 + qsub * 16 + lr) * 8) : zf;

    f32x4 O[2];
    f32x4 l4;
#pragma unroll
    for (int r = 0; r < 4; ++r) { O[0][r] = 0.f; O[1][r] = 0.f; l4[r] = 0.f; }

    // pipeline registers
    s16x8 phB_c[4], phB_n[4];
    s16x8 Gf_c[2][2], Gf_n[2][2];
#pragma unroll
    for (int ss = 0; ss < 4; ++ss)
        phB_c[ss] = (quad == 0) ? LD8G(ph + (size_t)(ss * 16 + lr) * 8) : zf;

    for (int t = 0; t < 8; ++t) {
        const int s0 = t * 64;
        const int sn = (t < 7 ? t + 1 : 7) * 64;

        // ---- prefetch next phB and this tile's Gf (consumed next iter) ----
#pragma unroll
        for (int ss = 0; ss < 4; ++ss)
            phB_n[ss] = (quad == 0) ? LD8G(ph + (size_t)(sn + ss * 16 + lr) * 8) : zf;
#pragma unroll
        for (int kc = 0; kc < 2; ++kc)
#pragma unroll
            for (int cs = 0; cs < 2; ++cs)
                Gf_n[kc][cs] = LD8G(gp + (size_t)(cs * 16 + lr) * NPS + s0 + kc * 32 + quad * 8);

        // ---- scores for tile t (phB_c prefetched last iter) ----
        const f32x4 zc = {0.f, 0.f, 0.f, 0.f};
        f32x4 S[4];
#pragma unroll
        for (int ss = 0; ss < 4; ++ss)
            S[ss] = __builtin_amdgcn_mfma_f32_16x16x32_bf16(thA, phB_c[ss], zc, 0, 0, 0);

        // ---- lagged PV for tile t-1 (P read from buf (t-1)&1, Gf_c prefetched) ----
        if (t > 0) {
            const unsigned short* Pb = Pw + ((t - 1) & 1) * 1152;
#pragma unroll
            for (int kc = 0; kc < 2; ++kc) {
                const s16x8 Pf = *(const s16x8*)(Pb + lr * 72 + kc * 32 + quad * 8);
#pragma unroll
                for (int cs = 0; cs < 2; ++cs)
                    O[cs] = __builtin_amdgcn_mfma_f32_16x16x32_bf16(Pf, Gf_c[kc][cs], O[cs], 0, 0, 0);
            }
        }

        // ---- p = exp2(S), accumulate l, store bf16 P to buf t&1 ----
        unsigned short* Pbw = Pw + (t & 1) * 1152;
#pragma unroll
        for (int ss = 0; ss < 4; ++ss)
#pragma unroll
            for (int r = 0; r < 4; ++r) {
                const float p = exp2f(S[ss][r]);
                l4[r] += p;
                Pbw[(quad * 4 + r) * 72 + ss * 16 + lr] =
                    (unsigned short)(__float_as_uint(p) >> 16);   // truncate
            }

        // ---- rotate pipeline ----
#pragma unroll
        for (int ss = 0; ss < 4; ++ss) phB_c[ss] = phB_n[ss];
#pragma unroll
        for (int kc = 0; kc < 2; ++kc)
#pragma unroll
            for (int cs = 0; cs < 2; ++cs) Gf_c[kc][cs] = Gf_n[kc][cs];
    }

    // ---- drain: PV for tile 7 ----
    {
        const unsigned short* Pb = Pw + (7 & 1) * 1152;
#pragma unroll
        for (int kc = 0; kc < 2; ++kc) {
            const s16x8 Pf = *(const s16x8*)(Pb + lr * 72 + kc * 32 + quad * 8);
#pragma unroll
            for (int cs = 0; cs < 2; ++cs)
                O[cs] = __builtin_amdgcn_mfma_f32_16x16x32_bf16(Pf, Gf_c[kc][cs], O[cs], 0, 0, 0);
        }
    }

    // l partial: butterfly-sum over the 16-lane s-groups (keep as partial —
    // the two s-halves combine through LDS below)
#pragma unroll
    for (int r = 0; r < 4; ++r) {
        float v = l4[r];
        v += __shfl_xor(v, 1);
        v += __shfl_xor(v, 2);
        v += __shfl_xor(v, 4);
        v += __shfl_xor(v, 8);
        l4[r] = v;
    }

    __syncthreads();                          // all waves past their last P read
    float* xO    = (float*)smem;              // [2 qsub][32 c][16 q]  floats [0,1024)
    float* otile = xO + 1024;                 // [32 c][36 q]          floats [1024,2176)
    float* xl    = xO + 2176;                 // [2 qsub][16 q]        floats [2176,2208)

    if (sh == 1) {
        // publish partial O and l
#pragma unroll
        for (int cs = 0; cs < 2; ++cs) {
            f32x4 v;
#pragma unroll
            for (int r = 0; r < 4; ++r) v[r] = O[cs][r];
            *(f32x4*)(xO + qsub * 512 + (cs * 16 + lr) * 16 + quad * 4) = v;
        }
        if (lr == 0) {
#pragma unroll
            for (int r = 0; r < 4; ++r) xl[qsub * 16 + quad * 4 + r] = l4[r];
        }
    }
    __syncthreads();
    if (sh == 0) {
        // combine halves, normalize, write otile
        f32x4 rl;
#pragma unroll
        for (int r = 0; r < 4; ++r)
            rl[r] = 1.f / (l4[r] + xl[qsub * 16 + quad * 4 + r]);
#pragma unroll
        for (int cs = 0; cs < 2; ++cs) {
            const f32x4 xv = *(const f32x4*)(xO + qsub * 512 + (cs * 16 + lr) * 16 + quad * 4);
            f32x4 v;
#pragma unroll
            for (int r = 0; r < 4; ++r) v[r] = (O[cs][r] + xv[r]) * rl[r];
            *(f32x4*)(otile + (cs * 16 + lr) * 36 + qsub * 16 + quad * 4) = v;
        }
    }
    __syncthreads();

    // Wo epilogue + residual.
    // wave w -> output channels [w*16, w*16+16); lane = (q = lane&31,
    // csplit = lane>>5 picks c-range half). Wo row index is wave-uniform x
    // unrolled j -> stays s_load. Partial over 16 c, combined via shfl_xor(32).
    const int qq = lane & 31;
    const int c0 = (lane >> 5) * 16;
    float acc[16];
#pragma unroll
    for (int j = 0; j < 16; ++j) acc[j] = 0.f;
    for (int ci = 0; ci < 16; ++ci) {
        const int c = c0 + ci;
        const float ov = otile[c * 36 + qq];
#pragma unroll
        for (int j = 0; j < 16; ++j)
            acc[j] += Wo[(wave * 16 + j) * 32 + c] * ov;   // s_load
    }
    const float gam = gamma_p[0];
#pragma unroll
    for (int j = 0; j < 16; ++j) {
        float v = acc[j] + __shfl_xor(acc[j], 32);
        if (lane < 32) {
            const size_t a = ((size_t)b * NC + wave * 16 + j) * HWs + q0 + qq;
            out[a] = gam * v + x[a];
        }
    }
}

extern "C" void kernel_launch(void* const* d_in, const int* in_sizes, int n_in,
                              void* d_out, int out_size, void* d_ws, size_t ws_size,
                              hipStream_t stream) {
    const float* x     = (const float*)d_in[0];
    const float* Wt    = (const float*)d_in[1];
    const float* Wp    = (const float*)d_in[2];
    const float* Wg    = (const float*)d_in[3];
    const float* Wo    = (const float*)d_in[4];
    const float* gamma = (const float*)d_in[5];
    float* out = (float*)d_out;
    unsigned short* ws = (unsigned short*)d_ws;

    k_proj<<<512, 256, 0, stream>>>(x, Wt, Wp, Wg, ws);
    k_attn<<<2048, 256, 0, stream>>>(x, Wo, gamma, ws, out);
}

// Round 3
// 133.009 us; speedup vs baseline: 2.1423x; 1.1305x over previous
//
#include <hip/hip_runtime.h>
#include <math.h>

// Problem constants
#define NB   16
#define NC   64
#define HWs  4096
#define NPS  1024
#define LOG2E 1.44269504088896341f

// ws layout in ushort (bf16 bit patterns)
static constexpr size_t PHI_OFF = (size_t)NB * HWs * 8;            // theta: [b][4096][8]
static constexpr size_t GT_OFF  = PHI_OFF + (size_t)NB * NPS * 8;  // phi:   [b][1024][8]
// gT: [b][32][1024]; total 1,179,648 ushorts = 2.25 MB

typedef short s16x8 __attribute__((ext_vector_type(8)));
typedef float f32x4 __attribute__((ext_vector_type(4)));

#define LD8G(p) (*(const s16x8*)(p))

__device__ inline unsigned short f2bf(float f) {
    unsigned int u = __float_as_uint(f);
    u += 0x7fffu + ((u >> 16) & 1u);          // RNE
    return (unsigned short)(u >> 16);
}
__device__ inline unsigned int pk2(float a, float b) {
    unsigned int ua = __float_as_uint(a); ua += 0x7fffu + ((ua >> 16) & 1u);
    unsigned int ub = __float_as_uint(b); ub += 0x7fffu + ((ub >> 16) & 1u);
    return (ua >> 16) | (ub & 0xffff0000u);
}

// ---------------------------------------------------------------------------
// Kernel 1 (v3): all projections in one pass, x staged through LDS.
// Unchanged (below top-5 cutoff; target once k_attn drops).
// ---------------------------------------------------------------------------
__global__ __launch_bounds__(256) void k_proj(
    const float* __restrict__ x, const float* __restrict__ Wt,
    const float* __restrict__ Wp, const float* __restrict__ Wg,
    unsigned short* __restrict__ ws)
{
    __shared__ float xs[64 * 128];            // 32 KB

    unsigned short* theta = ws;
    unsigned short* phi   = ws + PHI_OFF;
    unsigned short* gT    = ws + GT_OFF;

    const int tid = threadIdx.x;
    const int blk = blockIdx.x;
    const int b   = blk >> 5;
    const int rp  = blk & 31;                 // image rows {2rp, 2rp+1}

    // ---- stage x[b][ci][rp*128 .. +128) -> xs[ci][0..128) ----
    const float* xsrc = x + (size_t)b * NC * HWs + rp * 128;
#pragma unroll
    for (int i = 0; i < 8; ++i) {
        const int idx = i * 256 + tid;        // 0..2047 float4 slots
        const int ci  = idx >> 5;
        const int f4  = idx & 31;
        float4 v = *(const float4*)(xsrc + (size_t)ci * HWs + f4 * 4);
        *(float4*)(xs + ci * 128 + f4 * 4) = v;
    }
    __syncthreads();

    const int h    = tid & 127;
    // wave-uniform in fact (waves 0,1 -> 0; waves 2,3 -> 1); force to SGPR
    const int half = __builtin_amdgcn_readfirstlane(tid >> 7);
    const int row  = h & 1;
    const int col  = h >> 1;
    const int px   = row * 64 + col;

    float a8[8], ag[16];
#pragma unroll
    for (int j = 0; j < 8; ++j)  a8[j] = 0.f;
#pragma unroll
    for (int j = 0; j < 16; ++j) ag[j] = 0.f;

    const float* W8 = half ? Wp : Wt;         // scalar select (half is SGPR)
    const float* WG = Wg + half * 16 * NC;

#pragma unroll 4
    for (int ci = 0; ci < NC; ++ci) {
        const float xv = xs[ci * 128 + px];   // 2-way bank alias: free
#pragma unroll
        for (int j = 0; j < 8; ++j)  a8[j] += W8[j * NC + ci] * xv;   // s_load
#pragma unroll
        for (int j = 0; j < 16; ++j) ag[j] += WG[j * NC + ci] * xv;   // s_load
    }

    if (half == 0) {
        // theta: unpooled, scaled by log2e
        const int q = (2 * rp + row) * 64 + col;
        uint4 pkd;
        pkd.x = pk2(a8[0] * LOG2E, a8[1] * LOG2E);
        pkd.y = pk2(a8[2] * LOG2E, a8[3] * LOG2E);
        pkd.z = pk2(a8[4] * LOG2E, a8[5] * LOG2E);
        pkd.w = pk2(a8[6] * LOG2E, a8[7] * LOG2E);
        *(uint4*)(theta + ((size_t)b * HWs + q) * 8) = pkd;
    }

    // pooled max: row pair (h^1) then col pair (h^2) — both within-wave
#pragma unroll
    for (int j = 0; j < 8; ++j) {
        float v = a8[j];
        v = fmaxf(v, __shfl_xor(v, 1));
        v = fmaxf(v, __shfl_xor(v, 2));
        a8[j] = v;
    }
#pragma unroll
    for (int j = 0; j < 16; ++j) {
        float v = ag[j];
        v = fmaxf(v, __shfl_xor(v, 1));
        v = fmaxf(v, __shfl_xor(v, 2));
        ag[j] = v;
    }

    if ((h & 3) == 0) {
        const int ps = rp * 32 + (h >> 2);
        if (half == 1) {
            uint4 pkd;
            pkd.x = pk2(a8[0], a8[1]); pkd.y = pk2(a8[2], a8[3]);
            pkd.z = pk2(a8[4], a8[5]); pkd.w = pk2(a8[6], a8[7]);
            *(uint4*)(phi + ((size_t)b * NPS + ps) * 8) = pkd;
        }
#pragma unroll
        for (int j = 0; j < 16; ++j) {
            const int c = half * 16 + j;
            gT[((size_t)b * 32 + c) * NPS + ps] = f2bf(ag[j]);
        }
    }
}

// ---------------------------------------------------------------------------
// Kernel 2 (v6): v3 skeleton + REAL software pipeline.
// Round-7 post-mortem: v3 compiled to 60 VGPR but the loop's pipeline needs
// ~100 VGPRs live (phB x2 32, Gf x2 32, S 16, O 8, ...) — the allocator
// collapsed the prefetch (sank loads to uses), so every tile paid serial
// L2/LDS latency (~2500 cy/tile). v5's wave-split just multiplied the
// per-wave fixed overhead (fit: F ~ 10.7 tile-costs).
// v6: 1024 blocks x 4 waves (4 blk/CU = 4 waves/SIMD — needs only VGPR<=128),
// launch_bounds(256,4) raises the VGPR cap to 128 so the pipeline survives.
// Manual 2x-unrolled ping-pong regs (no rotate movs, static LDS buf offsets),
// unmasked phi loads (thA quad>=1 rows are zero, so 0*garbage=0), Pf LDS
// reads hoisted above QK MFMAs. Math identical to v3.
// Spill check: FETCH_SIZE must stay ~14 MB.
// ---------------------------------------------------------------------------
__global__ __launch_bounds__(256, 4) void k_attn(
    const float* __restrict__ x, const float* __restrict__ Wo,
    const float* __restrict__ gamma_p, const unsigned short* __restrict__ ws,
    float* __restrict__ out)
{
    __shared__ __align__(16) unsigned char smem[18432]; // P: 4 waves x 2 bufs x 16 x 72 x 2B; epilogue otile[32][68] f32

    const int tid  = threadIdx.x;
    const int wave = __builtin_amdgcn_readfirstlane(tid >> 6);
    const int lane = tid & 63;
    const int quad = lane >> 4, lr = lane & 15;
    const int blk  = blockIdx.x;
    const int b    = blk >> 6;
    const int q0   = (blk & 63) * 64;

    const unsigned short* th = ws + (size_t)b * HWs * 8;
    const unsigned short* ph = ws + PHI_OFF + (size_t)b * NPS * 8;
    const unsigned short* gp = ws + GT_OFF + (size_t)b * 32 * NPS;
    unsigned short* Pw = (unsigned short*)smem + wave * 2304;   // 2 bufs x [16 q][72 s]

    const s16x8 zf = {0, 0, 0, 0, 0, 0, 0, 0};
    const f32x4 zc = {0.f, 0.f, 0.f, 0.f};

    // theta A-fragment: A[m=q=lr][k=quad*8+j], real k<8 in quad 0
    const s16x8 thA = (quad == 0) ? LD8G(th + (size_t)(q0 + wave * 16 + lr) * 8) : zf;

    f32x4 O[2];
    f32x4 l4;
#pragma unroll
    for (int r = 0; r < 4; ++r) { O[0][r] = 0.f; O[1][r] = 0.f; l4[r] = 0.f; }

    // ping-pong pipeline registers
    s16x8 phB_e[4], phB_o[4];
    s16x8 Gf_e[2][2], Gf_o[2][2];

#define LOADPH(dst, tile)                                                     \
    _Pragma("unroll")                                                         \
    for (int ss = 0; ss < 4; ++ss)                                            \
        dst[ss] = LD8G(ph + (size_t)((tile) * 64 + ss * 16 + lr) * 8);

#define LOADG(dst, tile)                                                      \
    _Pragma("unroll")                                                         \
    for (int kc = 0; kc < 2; ++kc)                                            \
        _Pragma("unroll")                                                     \
        for (int cs = 0; cs < 2; ++cs)                                        \
            dst[kc][cs] = LD8G(gp + (size_t)(cs * 16 + lr) * NPS +            \
                               (tile) * 64 + kc * 32 + quad * 8);

#define QK(Sv, phB)                                                           \
    _Pragma("unroll")                                                         \
    for (int ss = 0; ss < 4; ++ss)                                            \
        Sv[ss] = __builtin_amdgcn_mfma_f32_16x16x32_bf16(thA, phB[ss], zc, 0, 0, 0);

#define EXPST(Sv, wbuf)                                                       \
    _Pragma("unroll")                                                         \
    for (int ss = 0; ss < 4; ++ss)                                            \
        _Pragma("unroll")                                                     \
        for (int r = 0; r < 4; ++r) {                                         \
            const float p = exp2f(Sv[ss][r]);                                 \
            l4[r] += p;                                                       \
            Pw[(wbuf) + (quad * 4 + r) * 72 + ss * 16 + lr] =                 \
                (unsigned short)(__float_as_uint(p) >> 16);                   \
        }

// One steady-state body: consume phCUR (tile curT), Gf PREV (tile curT-1),
// P from rbuf; issue Gf CUR (tile curT) + phNXT (tile curT+1); write P to wbuf.
#define BODY(phCUR, GfPREV, GfCUR, phNXT, curT, rbuf, wbuf)                   \
    {                                                                         \
        LOADG(GfCUR, (curT));                                                 \
        LOADPH(phNXT, (curT) + 1);                                            \
        const s16x8 Pf0 = *(const s16x8*)(Pw + (rbuf) + lr * 72 + quad * 8);  \
        const s16x8 Pf1 = *(const s16x8*)(Pw + (rbuf) + lr * 72 + 32 + quad * 8); \
        f32x4 S[4];                                                           \
        QK(S, phCUR);                                                         \
        _Pragma("unroll")                                                     \
        for (int cs = 0; cs < 2; ++cs)                                        \
            O[cs] = __builtin_amdgcn_mfma_f32_16x16x32_bf16(Pf0, GfPREV[0][cs], O[cs], 0, 0, 0); \
        _Pragma("unroll")                                                     \
        for (int cs = 0; cs < 2; ++cs)                                        \
            O[cs] = __builtin_amdgcn_mfma_f32_16x16x32_bf16(Pf1, GfPREV[1][cs], O[cs], 0, 0, 0); \
        EXPST(S, wbuf);                                                       \
    }

    // ---- prologue: tile 0 (no PV yet). P[0] -> buf0. ----
    LOADPH(phB_e, 0);
    {
        LOADG(Gf_e, 0);
        LOADPH(phB_o, 1);
        f32x4 S[4];
        QK(S, phB_e);
        EXPST(S, 0);
    }

    // ---- steady state: pairs (t odd, t+1 even), t = 1..13 ----
    for (int t = 1; t < 15; t += 2) {
        BODY(phB_o, Gf_e, Gf_o, phB_e, t,     0,    1152);   // odd:  read buf0, write buf1
        BODY(phB_e, Gf_o, Gf_e, phB_o, t + 1, 1152, 0);      // even: read buf1, write buf0
    }

    // ---- t = 15 (odd, no next-phi prefetch) ----
    {
        LOADG(Gf_o, 15);
        const s16x8 Pf0 = *(const s16x8*)(Pw + 0 + lr * 72 + quad * 8);
        const s16x8 Pf1 = *(const s16x8*)(Pw + 0 + lr * 72 + 32 + quad * 8);
        f32x4 S[4];
        QK(S, phB_o);
#pragma unroll
        for (int cs = 0; cs < 2; ++cs)
            O[cs] = __builtin_amdgcn_mfma_f32_16x16x32_bf16(Pf0, Gf_e[0][cs], O[cs], 0, 0, 0);
#pragma unroll
        for (int cs = 0; cs < 2; ++cs)
            O[cs] = __builtin_amdgcn_mfma_f32_16x16x32_bf16(Pf1, Gf_e[1][cs], O[cs], 0, 0, 0);
        EXPST(S, 1152);
    }

    // ---- drain: PV for tile 15 (P in buf1, Gf_o) ----
    {
        const s16x8 Pf0 = *(const s16x8*)(Pw + 1152 + lr * 72 + quad * 8);
        const s16x8 Pf1 = *(const s16x8*)(Pw + 1152 + lr * 72 + 32 + quad * 8);
#pragma unroll
        for (int cs = 0; cs < 2; ++cs)
            O[cs] = __builtin_amdgcn_mfma_f32_16x16x32_bf16(Pf0, Gf_o[0][cs], O[cs], 0, 0, 0);
#pragma unroll
        for (int cs = 0; cs < 2; ++cs)
            O[cs] = __builtin_amdgcn_mfma_f32_16x16x32_bf16(Pf1, Gf_o[1][cs], O[cs], 0, 0, 0);
    }

    // l: butterfly-sum over the 16-lane s-groups; O rows share the same q map
#pragma unroll
    for (int r = 0; r < 4; ++r) {
        float v = l4[r];
        v += __shfl_xor(v, 1);
        v += __shfl_xor(v, 2);
        v += __shfl_xor(v, 4);
        v += __shfl_xor(v, 8);
        l4[r] = 1.f / v;
    }

    __syncthreads();                          // all waves done with their Pw
    float* otile = (float*)smem;              // [32 c][68 q-stride]
#pragma unroll
    for (int cs = 0; cs < 2; ++cs) {
        f32x4 v;
#pragma unroll
        for (int r = 0; r < 4; ++r) v[r] = O[cs][r] * l4[r];
        *(f32x4*)(otile + (cs * 16 + lr) * 68 + wave * 16 + quad * 4) = v;
    }
    __syncthreads();

    // Wo epilogue + residual: thread = (q = tid&63, oc quarter = tid>>6)
    const int qq = tid & 63;
    const int quarter = __builtin_amdgcn_readfirstlane(tid >> 6); // SGPR -> s_load Wo
    float acc[16];
#pragma unroll
    for (int j = 0; j < 16; ++j) acc[j] = 0.f;
    for (int c = 0; c < 32; ++c) {
        const float ov = otile[c * 68 + qq];
#pragma unroll
        for (int j = 0; j < 16; ++j)
            acc[j] += Wo[(quarter * 16 + j) * 32 + c] * ov;   // s_load
    }
    const float gam = gamma_p[0];
#pragma unroll
    for (int j = 0; j < 16; ++j) {
        const size_t a = ((size_t)b * NC + quarter * 16 + j) * HWs + q0 + qq;
        out[a] = gam * acc[j] + x[a];
    }
}

extern "C" void kernel_launch(void* const* d_in, const int* in_sizes, int n_in,
                              void* d_out, int out_size, void* d_ws, size_t ws_size,
                              hipStream_t stream) {
    const float* x     = (const float*)d_in[0];
    const float* Wt    = (const float*)d_in[1];
    const float* Wp    = (const float*)d_in[2];
    const float* Wg    = (const float*)d_in[3];
    const float* Wo    = (const float*)d_in[4];
    const float* gamma = (const float*)d_in[5];
    float* out = (float*)d_out;
    unsigned short* ws = (unsigned short*)d_ws;

    k_proj<<<512, 256, 0, stream>>>(x, Wt, Wp, Wg, ws);
    k_attn<<<1024, 256, 0, stream>>>(x, Wo, gamma, ws, out);
}

// Round 4
// 127.154 us; speedup vs baseline: 2.2409x; 1.0460x over previous
//
#include <hip/hip_runtime.h>
#include <math.h>

// Problem constants
#define NB   16
#define NC   64
#define HWs  4096
#define NPS  1024
#define LOG2E 1.44269504088896341f

// ws layout in ushort (bf16 bit patterns)
static constexpr size_t PHI_OFF = (size_t)NB * HWs * 8;            // theta: [b][4096][8]
static constexpr size_t GT_OFF  = PHI_OFF + (size_t)NB * NPS * 8;  // phi:   [b][1024][8]
// gT: [b][32][1024]; total 1,179,648 ushorts = 2.25 MB

typedef short s16x8 __attribute__((ext_vector_type(8)));
typedef float f32x4 __attribute__((ext_vector_type(4)));

#define LD8G(p) (*(const s16x8*)(p))
#define SB()    __builtin_amdgcn_sched_barrier(0)

__device__ inline unsigned short f2bf(float f) {
    unsigned int u = __float_as_uint(f);
    u += 0x7fffu + ((u >> 16) & 1u);          // RNE
    return (unsigned short)(u >> 16);
}
__device__ inline unsigned int pk2(float a, float b) {
    unsigned int ua = __float_as_uint(a); ua += 0x7fffu + ((ua >> 16) & 1u);
    unsigned int ub = __float_as_uint(b); ub += 0x7fffu + ((ub >> 16) & 1u);
    return (ua >> 16) | (ub & 0xffff0000u);
}

// ---------------------------------------------------------------------------
// Kernel 1 (v4): half-split blocks for occupancy.
// Round-8 analysis: k_proj has been hiding at ~51 us just below the top-5
// cutoff (total 133 = 51.4 attn + ~51 proj + overhead). It ran 512 blocks =
// 2 blocks/CU = 8 waves/CU (25% cap), 2 waves/SIMD can't hide the
// s_load/ds_read chains. v4: block = (b, rp, half); half 0 -> theta + g[0:16],
// half 1 -> phi + g[16:32]; thread sub-half splits outputs (12 MACs/ci).
// 1024 blocks x 32KB LDS -> 4 resident/CU = 16 waves/CU, per-thread chain
// halved. Outputs disjoint across halves (no races); x staged twice
// (+16MB reads, L2-absorbed, HBM at 5%).
// ---------------------------------------------------------------------------
__global__ __launch_bounds__(256) void k_proj(
    const float* __restrict__ x, const float* __restrict__ Wt,
    const float* __restrict__ Wp, const float* __restrict__ Wg,
    unsigned short* __restrict__ ws)
{
    __shared__ float xs[64 * 128];            // 32 KB

    unsigned short* theta = ws;
    unsigned short* phi   = ws + PHI_OFF;
    unsigned short* gT    = ws + GT_OFF;

    const int tid  = threadIdx.x;
    const int blk  = blockIdx.x;
    const int b    = blk >> 6;
    const int rp   = (blk >> 1) & 31;         // image rows {2rp, 2rp+1}
    const int half = blk & 1;                 // block-uniform -> SGPR

    // ---- stage x[b][ci][rp*128 .. +128) -> xs[ci][0..128) ----
    const float* xsrc = x + (size_t)b * NC * HWs + rp * 128;
#pragma unroll
    for (int i = 0; i < 8; ++i) {
        const int idx = i * 256 + tid;        // 0..2047 float4 slots
        const int ci  = idx >> 5;
        const int f4  = idx & 31;
        float4 v = *(const float4*)(xsrc + (size_t)ci * HWs + f4 * 4);
        *(float4*)(xs + ci * 128 + f4 * 4) = v;
    }
    __syncthreads();

    const int h   = tid & 127;
    // wave-uniform (waves 0,1 -> 0; waves 2,3 -> 1); force to SGPR
    const int sub = __builtin_amdgcn_readfirstlane(tid >> 7);
    const int row = h & 1;
    const int col = h >> 1;
    const int px  = row * 64 + col;

    float a4[4], ag8[8];
#pragma unroll
    for (int j = 0; j < 4; ++j) a4[j] = 0.f;
#pragma unroll
    for (int j = 0; j < 8; ++j) ag8[j] = 0.f;

    const float* W8 = (half ? Wp : Wt) + sub * 4 * NC;   // scalar base
    const float* WG = Wg + (half * 16 + sub * 8) * NC;   // scalar base

#pragma unroll 4
    for (int ci = 0; ci < NC; ++ci) {
        const float xv = xs[ci * 128 + px];   // 2-way bank alias: free
#pragma unroll
        for (int j = 0; j < 4; ++j) a4[j] += W8[j * NC + ci] * xv;    // s_load
#pragma unroll
        for (int j = 0; j < 8; ++j) ag8[j] += WG[j * NC + ci] * xv;   // s_load
    }

    if (half == 0) {
        // theta: unpooled, scaled by log2e; channels sub*4 .. sub*4+4
        const int q = (2 * rp + row) * 64 + col;
        uint2 pkd;
        pkd.x = pk2(a4[0] * LOG2E, a4[1] * LOG2E);
        pkd.y = pk2(a4[2] * LOG2E, a4[3] * LOG2E);
        *(uint2*)(theta + ((size_t)b * HWs + q) * 8 + sub * 4) = pkd;
    } else {
        // phi needs pooling: row pair (h^1) then col pair (h^2), within-wave
#pragma unroll
        for (int j = 0; j < 4; ++j) {
            float v = a4[j];
            v = fmaxf(v, __shfl_xor(v, 1));
            v = fmaxf(v, __shfl_xor(v, 2));
            a4[j] = v;
        }
    }

    // g pooling (both halves)
#pragma unroll
    for (int j = 0; j < 8; ++j) {
        float v = ag8[j];
        v = fmaxf(v, __shfl_xor(v, 1));
        v = fmaxf(v, __shfl_xor(v, 2));
        ag8[j] = v;
    }

    if ((h & 3) == 0) {
        const int ps = rp * 32 + (h >> 2);
        if (half == 1) {
            uint2 pkd;
            pkd.x = pk2(a4[0], a4[1]);
            pkd.y = pk2(a4[2], a4[3]);
            *(uint2*)(phi + ((size_t)b * NPS + ps) * 8 + sub * 4) = pkd;
        }
#pragma unroll
        for (int j = 0; j < 8; ++j) {
            const int c = half * 16 + sub * 8 + j;
            gT[((size_t)b * 32 + c) * NPS + ps] = f2bf(ag8[j]);
        }
    }
}

// ---------------------------------------------------------------------------
// Kernel 2 (v7): v6 ping-pong + sched_barrier(0) fences.
// Round-8 post-mortem: v6 compiled to 44 VGPR — the machine scheduler sank
// every prefetch load to its use (source structure ignored), leaving a
// ~1900 cy serial chain per tile that 4 waves/SIMD fill to only 38%.
// v7: __builtin_amdgcn_sched_barrier(0) after each load-issue group pins
// loads a full tile ahead; waits land counted at first use. Verification:
// VGPR must rise to ~90-128 (pipeline survives). Math unchanged.
// ---------------------------------------------------------------------------
__global__ __launch_bounds__(256, 4) void k_attn(
    const float* __restrict__ x, const float* __restrict__ Wo,
    const float* __restrict__ gamma_p, const unsigned short* __restrict__ ws,
    float* __restrict__ out)
{
    __shared__ __align__(16) unsigned char smem[18432]; // P: 4 waves x 2 bufs x 16 x 72 x 2B; epilogue otile[32][68] f32

    const int tid  = threadIdx.x;
    const int wave = __builtin_amdgcn_readfirstlane(tid >> 6);
    const int lane = tid & 63;
    const int quad = lane >> 4, lr = lane & 15;
    const int blk  = blockIdx.x;
    const int b    = blk >> 6;
    const int q0   = (blk & 63) * 64;

    const unsigned short* th = ws + (size_t)b * HWs * 8;
    const unsigned short* ph = ws + PHI_OFF + (size_t)b * NPS * 8;
    const unsigned short* gp = ws + GT_OFF + (size_t)b * 32 * NPS;
    unsigned short* Pw = (unsigned short*)smem + wave * 2304;   // 2 bufs x [16 q][72 s]

    const s16x8 zf = {0, 0, 0, 0, 0, 0, 0, 0};
    const f32x4 zc = {0.f, 0.f, 0.f, 0.f};

    // theta A-fragment: A[m=q=lr][k=quad*8+j], real k<8 in quad 0
    const s16x8 thA = (quad == 0) ? LD8G(th + (size_t)(q0 + wave * 16 + lr) * 8) : zf;

    f32x4 O[2];
    f32x4 l4;
#pragma unroll
    for (int r = 0; r < 4; ++r) { O[0][r] = 0.f; O[1][r] = 0.f; l4[r] = 0.f; }

    // ping-pong pipeline registers
    s16x8 phB_e[4], phB_o[4];
    s16x8 Gf_e[2][2], Gf_o[2][2];

#define LOADPH(dst, tile)                                                     \
    _Pragma("unroll")                                                         \
    for (int ss = 0; ss < 4; ++ss)                                            \
        dst[ss] = LD8G(ph + (size_t)((tile) * 64 + ss * 16 + lr) * 8);

#define LOADG(dst, tile)                                                      \
    _Pragma("unroll")                                                         \
    for (int kc = 0; kc < 2; ++kc)                                            \
        _Pragma("unroll")                                                     \
        for (int cs = 0; cs < 2; ++cs)                                        \
            dst[kc][cs] = LD8G(gp + (size_t)(cs * 16 + lr) * NPS +            \
                               (tile) * 64 + kc * 32 + quad * 8);

#define QK(Sv, phB)                                                           \
    _Pragma("unroll")                                                         \
    for (int ss = 0; ss < 4; ++ss)                                            \
        Sv[ss] = __builtin_amdgcn_mfma_f32_16x16x32_bf16(thA, phB[ss], zc, 0, 0, 0);

#define EXPST(Sv, wbuf)                                                       \
    _Pragma("unroll")                                                         \
    for (int ss = 0; ss < 4; ++ss)                                            \
        _Pragma("unroll")                                                     \
        for (int r = 0; r < 4; ++r) {                                         \
            const float p = exp2f(Sv[ss][r]);                                 \
            l4[r] += p;                                                       \
            Pw[(wbuf) + (quad * 4 + r) * 72 + ss * 16 + lr] =                 \
                (unsigned short)(__float_as_uint(p) >> 16);                   \
        }

// One steady-state body: consume phCUR (tile curT), Gf PREV (tile curT-1),
// P from rbuf; issue Gf CUR (tile curT) + phNXT (tile curT+1); write P to wbuf.
// sched_barrier(0) pins the load-issue group above the MFMA/exp region so
// the scheduler cannot sink loads to their uses (the v3/v6 collapse).
#define BODY(phCUR, GfPREV, GfCUR, phNXT, curT, rbuf, wbuf)                   \
    {                                                                         \
        LOADG(GfCUR, (curT));                                                 \
        LOADPH(phNXT, (curT) + 1);                                            \
        const s16x8 Pf0 = *(const s16x8*)(Pw + (rbuf) + lr * 72 + quad * 8);  \
        const s16x8 Pf1 = *(const s16x8*)(Pw + (rbuf) + lr * 72 + 32 + quad * 8); \
        SB();                                                                 \
        f32x4 S[4];                                                           \
        QK(S, phCUR);                                                         \
        _Pragma("unroll")                                                     \
        for (int cs = 0; cs < 2; ++cs)                                        \
            O[cs] = __builtin_amdgcn_mfma_f32_16x16x32_bf16(Pf0, GfPREV[0][cs], O[cs], 0, 0, 0); \
        _Pragma("unroll")                                                     \
        for (int cs = 0; cs < 2; ++cs)                                        \
            O[cs] = __builtin_amdgcn_mfma_f32_16x16x32_bf16(Pf1, GfPREV[1][cs], O[cs], 0, 0, 0); \
        SB();                                                                 \
        EXPST(S, wbuf);                                                       \
    }

    // ---- prologue: tile 0 (no PV yet). P[0] -> buf0. ----
    LOADPH(phB_e, 0);
    {
        LOADG(Gf_e, 0);
        LOADPH(phB_o, 1);
        SB();
        f32x4 S[4];
        QK(S, phB_e);
        SB();
        EXPST(S, 0);
    }

    // ---- steady state: pairs (t odd, t+1 even), t = 1..13 ----
    for (int t = 1; t < 15; t += 2) {
        BODY(phB_o, Gf_e, Gf_o, phB_e, t,     0,    1152);   // odd:  read buf0, write buf1
        BODY(phB_e, Gf_o, Gf_e, phB_o, t + 1, 1152, 0);      // even: read buf1, write buf0
    }

    // ---- t = 15 (odd, no next-phi prefetch) ----
    {
        LOADG(Gf_o, 15);
        const s16x8 Pf0 = *(const s16x8*)(Pw + 0 + lr * 72 + quad * 8);
        const s16x8 Pf1 = *(const s16x8*)(Pw + 0 + lr * 72 + 32 + quad * 8);
        SB();
        f32x4 S[4];
        QK(S, phB_o);
#pragma unroll
        for (int cs = 0; cs < 2; ++cs)
            O[cs] = __builtin_amdgcn_mfma_f32_16x16x32_bf16(Pf0, Gf_e[0][cs], O[cs], 0, 0, 0);
#pragma unroll
        for (int cs = 0; cs < 2; ++cs)
            O[cs] = __builtin_amdgcn_mfma_f32_16x16x32_bf16(Pf1, Gf_e[1][cs], O[cs], 0, 0, 0);
        SB();
        EXPST(S, 1152);
    }

    // ---- drain: PV for tile 15 (P in buf1, Gf_o) ----
    {
        const s16x8 Pf0 = *(const s16x8*)(Pw + 1152 + lr * 72 + quad * 8);
        const s16x8 Pf1 = *(const s16x8*)(Pw + 1152 + lr * 72 + 32 + quad * 8);
#pragma unroll
        for (int cs = 0; cs < 2; ++cs)
            O[cs] = __builtin_amdgcn_mfma_f32_16x16x32_bf16(Pf0, Gf_o[0][cs], O[cs], 0, 0, 0);
#pragma unroll
        for (int cs = 0; cs < 2; ++cs)
            O[cs] = __builtin_amdgcn_mfma_f32_16x16x32_bf16(Pf1, Gf_o[1][cs], O[cs], 0, 0, 0);
    }

    // l: butterfly-sum over the 16-lane s-groups; O rows share the same q map
#pragma unroll
    for (int r = 0; r < 4; ++r) {
        float v = l4[r];
        v += __shfl_xor(v, 1);
        v += __shfl_xor(v, 2);
        v += __shfl_xor(v, 4);
        v += __shfl_xor(v, 8);
        l4[r] = 1.f / v;
    }

    __syncthreads();                          // all waves done with their Pw
    float* otile = (float*)smem;              // [32 c][68 q-stride]
#pragma unroll
    for (int cs = 0; cs < 2; ++cs) {
        f32x4 v;
#pragma unroll
        for (int r = 0; r < 4; ++r) v[r] = O[cs][r] * l4[r];
        *(f32x4*)(otile + (cs * 16 + lr) * 68 + wave * 16 + quad * 4) = v;
    }
    __syncthreads();

    // Wo epilogue + residual: thread = (q = tid&63, oc quarter = tid>>6)
    const int qq = tid & 63;
    const int quarter = __builtin_amdgcn_readfirstlane(tid >> 6); // SGPR -> s_load Wo
    float acc[16];
#pragma unroll
    for (int j = 0; j < 16; ++j) acc[j] = 0.f;
    for (int c = 0; c < 32; ++c) {
        const float ov = otile[c * 68 + qq];
#pragma unroll
        for (int j = 0; j < 16; ++j)
            acc[j] += Wo[(quarter * 16 + j) * 32 + c] * ov;   // s_load
    }
    const float gam = gamma_p[0];
#pragma unroll
    for (int j = 0; j < 16; ++j) {
        const size_t a = ((size_t)b * NC + quarter * 16 + j) * HWs + q0 + qq;
        out[a] = gam * acc[j] + x[a];
    }
}

extern "C" void kernel_launch(void* const* d_in, const int* in_sizes, int n_in,
                              void* d_out, int out_size, void* d_ws, size_t ws_size,
                              hipStream_t stream) {
    const float* x     = (const float*)d_in[0];
    const float* Wt    = (const float*)d_in[1];
    const float* Wp    = (const float*)d_in[2];
    const float* Wg    = (const float*)d_in[3];
    const float* Wo    = (const float*)d_in[4];
    const float* gamma = (const float*)d_in[5];
    float* out = (float*)d_out;
    unsigned short* ws = (unsigned short*)d_ws;

    k_proj<<<1024, 256, 0, stream>>>(x, Wt, Wp, Wg, ws);
    k_attn<<<1024, 256, 0, stream>>>(x, Wo, gamma, ws, out);
}

// Round 5
// 126.762 us; speedup vs baseline: 2.2478x; 1.0031x over previous
//
#include <hip/hip_runtime.h>
#include <math.h>

// Problem constants
#define NB   16
#define NC   64
#define HWs  4096
#define NPS  1024
#define LOG2E 1.44269504088896341f

// ws layout in ushort (bf16 bit patterns)
static constexpr size_t PHI_OFF = (size_t)NB * HWs * 8;            // theta: [b][4096][8]
static constexpr size_t GT_OFF  = PHI_OFF + (size_t)NB * NPS * 8;  // phi:   [b][1024][8]
// gT: [b][32][1024]; total 1,179,648 ushorts = 2.25 MB

typedef short s16x8 __attribute__((ext_vector_type(8)));
typedef float f32x4 __attribute__((ext_vector_type(4)));

#define LD8G(p) (*(const s16x8*)(p))
#define SB()    __builtin_amdgcn_sched_barrier(0)

__device__ inline unsigned short f2bf(float f) {
    unsigned int u = __float_as_uint(f);
    u += 0x7fffu + ((u >> 16) & 1u);          // RNE
    return (unsigned short)(u >> 16);
}
__device__ inline unsigned int pk2(float a, float b) {
    unsigned int ua = __float_as_uint(a); ua += 0x7fffu + ((ua >> 16) & 1u);
    unsigned int ub = __float_as_uint(b); ub += 0x7fffu + ((ub >> 16) & 1u);
    return (ua >> 16) | (ub & 0xffff0000u);
}

// ---------------------------------------------------------------------------
// Kernel 1 (v4 + waves_per_eu pin): half-split blocks for occupancy.
// Grid = 1024 blocks = 4 blocks/CU = 4 waves/EU; amdgpu_waves_per_eu(4,4)
// stops the scheduler from squeezing VGPRs below what the grid can use
// (same mechanism as k_attn round-9 finding; unmeasured here but bounded —
// cannot reduce achieved occupancy since the grid caps it at 4).
// ---------------------------------------------------------------------------
__global__ __launch_bounds__(256) __attribute__((amdgpu_waves_per_eu(4, 4)))
void k_proj(
    const float* __restrict__ x, const float* __restrict__ Wt,
    const float* __restrict__ Wp, const float* __restrict__ Wg,
    unsigned short* __restrict__ ws)
{
    __shared__ float xs[64 * 128];            // 32 KB

    unsigned short* theta = ws;
    unsigned short* phi   = ws + PHI_OFF;
    unsigned short* gT    = ws + GT_OFF;

    const int tid  = threadIdx.x;
    const int blk  = blockIdx.x;
    const int b    = blk >> 6;
    const int rp   = (blk >> 1) & 31;         // image rows {2rp, 2rp+1}
    const int half = blk & 1;                 // block-uniform -> SGPR

    // ---- stage x[b][ci][rp*128 .. +128) -> xs[ci][0..128) ----
    const float* xsrc = x + (size_t)b * NC * HWs + rp * 128;
#pragma unroll
    for (int i = 0; i < 8; ++i) {
        const int idx = i * 256 + tid;        // 0..2047 float4 slots
        const int ci  = idx >> 5;
        const int f4  = idx & 31;
        float4 v = *(const float4*)(xsrc + (size_t)ci * HWs + f4 * 4);
        *(float4*)(xs + ci * 128 + f4 * 4) = v;
    }
    __syncthreads();

    const int h   = tid & 127;
    // wave-uniform (waves 0,1 -> 0; waves 2,3 -> 1); force to SGPR
    const int sub = __builtin_amdgcn_readfirstlane(tid >> 7);
    const int row = h & 1;
    const int col = h >> 1;
    const int px  = row * 64 + col;

    float a4[4], ag8[8];
#pragma unroll
    for (int j = 0; j < 4; ++j) a4[j] = 0.f;
#pragma unroll
    for (int j = 0; j < 8; ++j) ag8[j] = 0.f;

    const float* W8 = (half ? Wp : Wt) + sub * 4 * NC;   // scalar base
    const float* WG = Wg + (half * 16 + sub * 8) * NC;   // scalar base

#pragma unroll 4
    for (int ci = 0; ci < NC; ++ci) {
        const float xv = xs[ci * 128 + px];   // 2-way bank alias: free
#pragma unroll
        for (int j = 0; j < 4; ++j) a4[j] += W8[j * NC + ci] * xv;    // s_load
#pragma unroll
        for (int j = 0; j < 8; ++j) ag8[j] += WG[j * NC + ci] * xv;   // s_load
    }

    if (half == 0) {
        // theta: unpooled, scaled by log2e; channels sub*4 .. sub*4+4
        const int q = (2 * rp + row) * 64 + col;
        uint2 pkd;
        pkd.x = pk2(a4[0] * LOG2E, a4[1] * LOG2E);
        pkd.y = pk2(a4[2] * LOG2E, a4[3] * LOG2E);
        *(uint2*)(theta + ((size_t)b * HWs + q) * 8 + sub * 4) = pkd;
    } else {
        // phi needs pooling: row pair (h^1) then col pair (h^2), within-wave
#pragma unroll
        for (int j = 0; j < 4; ++j) {
            float v = a4[j];
            v = fmaxf(v, __shfl_xor(v, 1));
            v = fmaxf(v, __shfl_xor(v, 2));
            a4[j] = v;
        }
    }

    // g pooling (both halves)
#pragma unroll
    for (int j = 0; j < 8; ++j) {
        float v = ag8[j];
        v = fmaxf(v, __shfl_xor(v, 1));
        v = fmaxf(v, __shfl_xor(v, 2));
        ag8[j] = v;
    }

    if ((h & 3) == 0) {
        const int ps = rp * 32 + (h >> 2);
        if (half == 1) {
            uint2 pkd;
            pkd.x = pk2(a4[0], a4[1]);
            pkd.y = pk2(a4[2], a4[3]);
            *(uint2*)(phi + ((size_t)b * NPS + ps) * 8 + sub * 4) = pkd;
        }
#pragma unroll
        for (int j = 0; j < 8; ++j) {
            const int c = half * 16 + sub * 8 + j;
            gT[((size_t)b * 32 + c) * NPS + ps] = f2bf(ag8[j]);
        }
    }
}

// ---------------------------------------------------------------------------
// Kernel 2 (v8): v7 + amdgpu_waves_per_eu(4,4) + contiguous-Wo epilogue.
// Round-9 post-mortem: v7 compiled to 64 VGPR — launch_bounds(256,4) only
// sets MIN waves/EU; the scheduler targeted 8 waves/EU (64 VGPR) on its own,
// serializing the pipeline (50 base VGPR + 14 spare = ~3 loads in flight).
// The grid supplies only 4 waves/EU (1024 blk = 4 blk/CU x 4 waves /4 SIMD),
// so that occupancy headroom is unusable. waves_per_eu(4,4) pins the target:
// budget 128 VGPR, ping-pong state (~119) survives. sched_barriers keep
// issue order. Epilogue: otile -> 32 VGPRs once, then per-j contiguous Wo
// rows (s_load_dwordx16) instead of 512 scattered s_load_dword.
// Decisive experiment: VGPR must rise to ~110-128. If dur doesn't follow,
// latency is NOT the load pipeline -> pivot to cache-residency theory.
// Spill tripwire: FETCH_SIZE must stay ~14 MB.
// ---------------------------------------------------------------------------
__global__ __launch_bounds__(256) __attribute__((amdgpu_waves_per_eu(4, 4)))
void k_attn(
    const float* __restrict__ x, const float* __restrict__ Wo,
    const float* __restrict__ gamma_p, const unsigned short* __restrict__ ws,
    float* __restrict__ out)
{
    __shared__ __align__(16) unsigned char smem[18432]; // P: 4 waves x 2 bufs x 16 x 72 x 2B; epilogue otile[32][68] f32

    const int tid  = threadIdx.x;
    const int wave = __builtin_amdgcn_readfirstlane(tid >> 6);
    const int lane = tid & 63;
    const int quad = lane >> 4, lr = lane & 15;
    const int blk  = blockIdx.x;
    const int b    = blk >> 6;
    const int q0   = (blk & 63) * 64;

    const unsigned short* th = ws + (size_t)b * HWs * 8;
    const unsigned short* ph = ws + PHI_OFF + (size_t)b * NPS * 8;
    const unsigned short* gp = ws + GT_OFF + (size_t)b * 32 * NPS;
    unsigned short* Pw = (unsigned short*)smem + wave * 2304;   // 2 bufs x [16 q][72 s]

    const s16x8 zf = {0, 0, 0, 0, 0, 0, 0, 0};
    const f32x4 zc = {0.f, 0.f, 0.f, 0.f};

    // theta A-fragment: A[m=q=lr][k=quad*8+j], real k<8 in quad 0
    const s16x8 thA = (quad == 0) ? LD8G(th + (size_t)(q0 + wave * 16 + lr) * 8) : zf;

    f32x4 O[2];
    f32x4 l4;
#pragma unroll
    for (int r = 0; r < 4; ++r) { O[0][r] = 0.f; O[1][r] = 0.f; l4[r] = 0.f; }

    // ping-pong pipeline registers
    s16x8 phB_e[4], phB_o[4];
    s16x8 Gf_e[2][2], Gf_o[2][2];

#define LOADPH(dst, tile)                                                     \
    _Pragma("unroll")                                                         \
    for (int ss = 0; ss < 4; ++ss)                                            \
        dst[ss] = LD8G(ph + (size_t)((tile) * 64 + ss * 16 + lr) * 8);

#define LOADG(dst, tile)                                                      \
    _Pragma("unroll")                                                         \
    for (int kc = 0; kc < 2; ++kc)                                            \
        _Pragma("unroll")                                                     \
        for (int cs = 0; cs < 2; ++cs)                                        \
            dst[kc][cs] = LD8G(gp + (size_t)(cs * 16 + lr) * NPS +            \
                               (tile) * 64 + kc * 32 + quad * 8);

#define QK(Sv, phB)                                                           \
    _Pragma("unroll")                                                         \
    for (int ss = 0; ss < 4; ++ss)                                            \
        Sv[ss] = __builtin_amdgcn_mfma_f32_16x16x32_bf16(thA, phB[ss], zc, 0, 0, 0);

#define EXPST(Sv, wbuf)                                                       \
    _Pragma("unroll")                                                         \
    for (int ss = 0; ss < 4; ++ss)                                            \
        _Pragma("unroll")                                                     \
        for (int r = 0; r < 4; ++r) {                                         \
            const float p = exp2f(Sv[ss][r]);                                 \
            l4[r] += p;                                                       \
            Pw[(wbuf) + (quad * 4 + r) * 72 + ss * 16 + lr] =                 \
                (unsigned short)(__float_as_uint(p) >> 16);                   \
        }

// One steady-state body: consume phCUR (tile curT), Gf PREV (tile curT-1),
// P from rbuf; issue Gf CUR (tile curT) + phNXT (tile curT+1); write P to wbuf.
// sched_barrier(0) pins the load-issue group above the MFMA/exp region.
#define BODY(phCUR, GfPREV, GfCUR, phNXT, curT, rbuf, wbuf)                   \
    {                                                                         \
        LOADG(GfCUR, (curT));                                                 \
        LOADPH(phNXT, (curT) + 1);                                            \
        const s16x8 Pf0 = *(const s16x8*)(Pw + (rbuf) + lr * 72 + quad * 8);  \
        const s16x8 Pf1 = *(const s16x8*)(Pw + (rbuf) + lr * 72 + 32 + quad * 8); \
        SB();                                                                 \
        f32x4 S[4];                                                           \
        QK(S, phCUR);                                                         \
        _Pragma("unroll")                                                     \
        for (int cs = 0; cs < 2; ++cs)                                        \
            O[cs] = __builtin_amdgcn_mfma_f32_16x16x32_bf16(Pf0, GfPREV[0][cs], O[cs], 0, 0, 0); \
        _Pragma("unroll")                                                     \
        for (int cs = 0; cs < 2; ++cs)                                        \
            O[cs] = __builtin_amdgcn_mfma_f32_16x16x32_bf16(Pf1, GfPREV[1][cs], O[cs], 0, 0, 0); \
        SB();                                                                 \
        EXPST(S, wbuf);                                                       \
    }

    // ---- prologue: tile 0 (no PV yet). P[0] -> buf0. ----
    LOADPH(phB_e, 0);
    {
        LOADG(Gf_e, 0);
        LOADPH(phB_o, 1);
        SB();
        f32x4 S[4];
        QK(S, phB_e);
        SB();
        EXPST(S, 0);
    }

    // ---- steady state: pairs (t odd, t+1 even), t = 1..13 ----
    for (int t = 1; t < 15; t += 2) {
        BODY(phB_o, Gf_e, Gf_o, phB_e, t,     0,    1152);   // odd:  read buf0, write buf1
        BODY(phB_e, Gf_o, Gf_e, phB_o, t + 1, 1152, 0);      // even: read buf1, write buf0
    }

    // ---- t = 15 (odd, no next-phi prefetch) ----
    {
        LOADG(Gf_o, 15);
        const s16x8 Pf0 = *(const s16x8*)(Pw + 0 + lr * 72 + quad * 8);
        const s16x8 Pf1 = *(const s16x8*)(Pw + 0 + lr * 72 + 32 + quad * 8);
        SB();
        f32x4 S[4];
        QK(S, phB_o);
#pragma unroll
        for (int cs = 0; cs < 2; ++cs)
            O[cs] = __builtin_amdgcn_mfma_f32_16x16x32_bf16(Pf0, Gf_e[0][cs], O[cs], 0, 0, 0);
#pragma unroll
        for (int cs = 0; cs < 2; ++cs)
            O[cs] = __builtin_amdgcn_mfma_f32_16x16x32_bf16(Pf1, Gf_e[1][cs], O[cs], 0, 0, 0);
        SB();
        EXPST(S, 1152);
    }

    // ---- drain: PV for tile 15 (P in buf1, Gf_o) ----
    {
        const s16x8 Pf0 = *(const s16x8*)(Pw + 1152 + lr * 72 + quad * 8);
        const s16x8 Pf1 = *(const s16x8*)(Pw + 1152 + lr * 72 + 32 + quad * 8);
#pragma unroll
        for (int cs = 0; cs < 2; ++cs)
            O[cs] = __builtin_amdgcn_mfma_f32_16x16x32_bf16(Pf0, Gf_o[0][cs], O[cs], 0, 0, 0);
#pragma unroll
        for (int cs = 0; cs < 2; ++cs)
            O[cs] = __builtin_amdgcn_mfma_f32_16x16x32_bf16(Pf1, Gf_o[1][cs], O[cs], 0, 0, 0);
    }

    // l: butterfly-sum over the 16-lane s-groups; O rows share the same q map
#pragma unroll
    for (int r = 0; r < 4; ++r) {
        float v = l4[r];
        v += __shfl_xor(v, 1);
        v += __shfl_xor(v, 2);
        v += __shfl_xor(v, 4);
        v += __shfl_xor(v, 8);
        l4[r] = 1.f / v;
    }

    __syncthreads();                          // all waves done with their Pw
    float* otile = (float*)smem;              // [32 c][68 q-stride]
#pragma unroll
    for (int cs = 0; cs < 2; ++cs) {
        f32x4 v;
#pragma unroll
        for (int r = 0; r < 4; ++r) v[r] = O[cs][r] * l4[r];
        *(f32x4*)(otile + (cs * 16 + lr) * 68 + wave * 16 + quad * 4) = v;
    }
    __syncthreads();

    // Wo epilogue + residual: thread = (q = tid&63, oc quarter = tid>>6).
    // otile row -> 32 VGPRs once; per-j Wo rows are CONTIGUOUS 32-float
    // s_loads (v7 had 512 scattered s_load_dword: 16 strided dwords per
    // c-iteration, each with its own lgkm wait chain).
    const int qq = tid & 63;
    const int quarter = __builtin_amdgcn_readfirstlane(tid >> 6); // SGPR -> s_load Wo
    float ov[32];
#pragma unroll
    for (int c = 0; c < 32; ++c) ov[c] = otile[c * 68 + qq];
    const float gam = gamma_p[0];
#pragma unroll
    for (int j = 0; j < 16; ++j) {
        const float* wrow = Wo + (size_t)(quarter * 16 + j) * 32;  // contiguous
        float a = 0.f;
#pragma unroll
        for (int c = 0; c < 32; ++c) a += wrow[c] * ov[c];         // s_load x16
        const size_t ad = ((size_t)b * NC + quarter * 16 + j) * HWs + q0 + qq;
        out[ad] = gam * a + x[ad];
    }
}

extern "C" void kernel_launch(void* const* d_in, const int* in_sizes, int n_in,
                              void* d_out, int out_size, void* d_ws, size_t ws_size,
                              hipStream_t stream) {
    const float* x     = (const float*)d_in[0];
    const float* Wt    = (const float*)d_in[1];
    const float* Wp    = (const float*)d_in[2];
    const float* Wg    = (const float*)d_in[3];
    const float* Wo    = (const float*)d_in[4];
    const float* gamma = (const float*)d_in[5];
    float* out = (float*)d_out;
    unsigned short* ws = (unsigned short*)d_ws;

    k_proj<<<1024, 256, 0, stream>>>(x, Wt, Wp, Wg, ws);
    k_attn<<<1024, 256, 0, stream>>>(x, Wo, gamma, ws, out);
}